// Round 1
// baseline (79.794 us; speedup 1.0000x reference)
//
#include <hip/hip_runtime.h>
#include <hip/hip_bf16.h>
#include <stdint.h>

#define N_ROWS 1024
#define IN_F   1024
#define OUT_F  128
#define KDIM   16
#define NCOL   (OUT_F * KDIM)          // 2048
#define OUT_STRIDE (IN_F + OUT_F)      // 1152

typedef __attribute__((ext_vector_type(8))) short bf16x8;
typedef __attribute__((ext_vector_type(4))) short s16x4;
typedef __attribute__((ext_vector_type(4))) float f32x4;

__device__ __forceinline__ short f2b(float f) {
    // round-to-nearest-even fp32 -> bf16 (data is finite; no NaN handling needed)
    uint32_t u = __float_as_uint(f);
    uint32_t r = u + 0x7fffu + ((u >> 16) & 1u);
    return (short)(r >> 16);
}
__device__ __forceinline__ float b2f(short s) {
    return __uint_as_float(((uint32_t)(uint16_t)s) << 16);
}

// ---------------------------------------------------------------------------
// kx: out[:, :1024] = x (exact fp32 copy) and xb = bf16(x)
// grid 1024 x 256 threads, one float4 per thread
__global__ __launch_bounds__(256) void kx_cast_copy(const float* __restrict__ x,
                                                    float* __restrict__ out,
                                                    short* __restrict__ xb) {
    int id  = blockIdx.x * 256 + threadIdx.x;     // 0 .. 1024*256-1
    int row = id >> 8;
    int c4  = id & 255;
    float4 v = *reinterpret_cast<const float4*>(x + row * IN_F + c4 * 4);
    *reinterpret_cast<float4*>(out + row * OUT_STRIDE + c4 * 4) = v;
    s16x4 h;
    h[0] = f2b(v.x); h[1] = f2b(v.y); h[2] = f2b(v.z); h[3] = f2b(v.w);
    *reinterpret_cast<s16x4*>(xb + row * IN_F + c4 * 4) = h;
}

// ---------------------------------------------------------------------------
// k0: Tt[col][k] = bf16(T[k][col])  (transpose + cast), LDS-tiled 64x64
#define TK 64
#define TC 64
#define TSTR 72   // shorts per LDS row (144 B: 16B-aligned, 36-bank stride)
__global__ __launch_bounds__(256) void k0_transpose(const float* __restrict__ T,
                                                    short* __restrict__ Tt) {
    __shared__ short lds[TC * TSTR];
    int kbase = blockIdx.y * TK;
    int cbase = blockIdx.x * TC;
    int t = threadIdx.x;
    // read 64(k) x 64(col) fp32 tile, coalesced float4
    for (int it = 0; it < 4; ++it) {
        int id = t + it * 256;          // 0..1023
        int k  = id >> 4;               // 0..63
        int c4 = id & 15;               // 0..15
        float4 v = *reinterpret_cast<const float4*>(T + (size_t)(kbase + k) * NCOL + cbase + c4 * 4);
        int c0 = c4 * 4;
        lds[(c0 + 0) * TSTR + k] = f2b(v.x);
        lds[(c0 + 1) * TSTR + k] = f2b(v.y);
        lds[(c0 + 2) * TSTR + k] = f2b(v.z);
        lds[(c0 + 3) * TSTR + k] = f2b(v.w);
    }
    __syncthreads();
    // write out 64 cols x 64 k bf16, 16B chunks, coalesced
    for (int it = 0; it < 2; ++it) {
        int id   = t + it * 256;        // 0..511
        int col  = id >> 3;             // 0..63
        int part = id & 7;              // 0..7
        bf16x8 w = *reinterpret_cast<const bf16x8*>(&lds[col * TSTR + part * 8]);
        *reinterpret_cast<bf16x8*>(Tt + (size_t)(cbase + col) * IN_F + kbase + part * 8) = w;
    }
}

// ---------------------------------------------------------------------------
// k1: M = xb @ T via bf16 MFMA 16x16x32.  Tile 64(M) x 128(N), BK=32,
// 4 waves as 2x2 (each 32x64).  Output stored as Mws[b][row][k] bf16.
#define BM 64
#define BN 128
#define BK 32
#define ASTR 40   // shorts per LDS row (80 B, 16B-aligned)
#define BSTR 40
__global__ __launch_bounds__(256) void k1_gemm(const short* __restrict__ xb,
                                               const short* __restrict__ Tt,
                                               short* __restrict__ Mws) {
    __shared__ short Al[BM * ASTR];   //  5120 B
    __shared__ short Bl[BN * BSTR];   // 10240 B
    int t   = threadIdx.x;
    int l   = t & 63;
    int w   = t >> 6;
    int wr  = w >> 1, wc = w & 1;
    int g   = l >> 4, r16 = l & 15;
    int rowbase = blockIdx.y * BM;
    int colbase = blockIdx.x * BN;
    f32x4 acc[2][4] = {};

    for (int kt = 0; kt < IN_F; kt += BK) {
        __syncthreads();
        {   // stage A: 64 rows x 32 k bf16 = 256 x 16B chunks
            int row = t >> 2, part = t & 3;
            bf16x8 v = *reinterpret_cast<const bf16x8*>(xb + (size_t)(rowbase + row) * IN_F + kt + part * 8);
            *reinterpret_cast<bf16x8*>(&Al[row * ASTR + part * 8]) = v;
        }
        for (int c = t; c < 512; c += 256) {  // stage B: 128 cols x 32 k
            int col = c >> 2, part = c & 3;
            bf16x8 v = *reinterpret_cast<const bf16x8*>(Tt + (size_t)(colbase + col) * IN_F + kt + part * 8);
            *reinterpret_cast<bf16x8*>(&Bl[col * BSTR + part * 8]) = v;
        }
        __syncthreads();
        bf16x8 a[2], b[4];
        #pragma unroll
        for (int m = 0; m < 2; ++m)
            a[m] = *reinterpret_cast<const bf16x8*>(&Al[(wr * 32 + m * 16 + r16) * ASTR + g * 8]);
        #pragma unroll
        for (int n = 0; n < 4; ++n)
            b[n] = *reinterpret_cast<const bf16x8*>(&Bl[(wc * 64 + n * 16 + r16) * BSTR + g * 8]);
        #pragma unroll
        for (int m = 0; m < 2; ++m)
            #pragma unroll
            for (int n = 0; n < 4; ++n)
                acc[m][n] = __builtin_amdgcn_mfma_f32_16x16x32_bf16(a[m], b[n], acc[m][n], 0, 0, 0);
    }

    // epilogue: C[row][col] -> Mws[(col>>4)][row][col&15] bf16
    #pragma unroll
    for (int m = 0; m < 2; ++m)
        #pragma unroll
        for (int n = 0; n < 4; ++n) {
            int col = colbase + wc * 64 + n * 16 + r16;
            int bb  = col >> 4, kk = col & 15;
            #pragma unroll
            for (int r = 0; r < 4; ++r) {
                int row = rowbase + wr * 32 + m * 16 + g * 4 + r;
                Mws[(size_t)((bb << 10) + row) * KDIM + kk] = f2b(acc[m][n][r]);
            }
        }
}

// ---------------------------------------------------------------------------
// k2: per (b, row-chunk): o[i,b] = sum_{j != i} exp(-max(sq_i+sq_j-2*M_i.M_j,0))
// Gram tiles via mfma 16x16x32 with K zero-padded to 32 (lanes g>=2 zero).
#define MSTR 24   // shorts per LDS row (48 B, 16B-aligned)
__global__ __launch_bounds__(256) void k2_kernelsum(const short* __restrict__ Mws,
                                                    float* __restrict__ out) {
    __shared__ short Ml[N_ROWS * MSTR];  // 49152 B
    __shared__ float sq[N_ROWS];         //  4096 B
    int b     = blockIdx.y;
    int chunk = blockIdx.x;              // 0..7, 128 rows each
    int t = threadIdx.x;
    const short* Mb = Mws + ((size_t)b << 10) * KDIM;

    for (int c = t; c < 2048; c += 256) {        // stage M_b: 1024 x 16 bf16
        int row = c >> 1, part = c & 1;
        bf16x8 v = *reinterpret_cast<const bf16x8*>(Mb + row * KDIM + part * 8);
        *reinterpret_cast<bf16x8*>(&Ml[row * MSTR + part * 8]) = v;
    }
    __syncthreads();
    for (int r = t; r < N_ROWS; r += 256) {      // sq from the staged bf16 M
        const short* mr = &Ml[r * MSTR];
        float s = 0.f;
        #pragma unroll
        for (int k = 0; k < KDIM; ++k) { float f = b2f(mr[k]); s += f * f; }
        sq[r] = s;
    }
    __syncthreads();

    int l = t & 63, w = t >> 6;
    int g = l >> 4, r16 = l & 15;
    for (int itl = 0; itl < 2; ++itl) {
        int irow = chunk * 128 + (w * 2 + itl) * 16;   // global i-tile base
        bf16x8 a = {};
        if (g < 2) a = *reinterpret_cast<const bf16x8*>(&Ml[(irow + r16) * MSTR + g * 8]);
        float sqi[4];
        #pragma unroll
        for (int r = 0; r < 4; ++r) sqi[r] = sq[irow + g * 4 + r];
        float osum[4] = {0.f, 0.f, 0.f, 0.f};

        for (int jt = 0; jt < 64; ++jt) {
            int jrow = jt * 16;
            bf16x8 bb = {};
            if (g < 2) bb = *reinterpret_cast<const bf16x8*>(&Ml[(jrow + r16) * MSTR + g * 8]);
            f32x4 accz = {};
            f32x4 c = __builtin_amdgcn_mfma_f32_16x16x32_bf16(a, bb, accz, 0, 0, 0);
            float sqj = sq[jrow + r16];
            float d0 = sqi[0] + sqj - 2.f * c[0];
            float d1 = sqi[1] + sqj - 2.f * c[1];
            float d2 = sqi[2] + sqj - 2.f * c[2];
            float d3 = sqi[3] + sqj - 2.f * c[3];
            float dmin = fminf(fminf(d0, d1), fminf(d2, d3));
            if (__ballot(dmin < 88.0f)) {        // ~never taken on this data
                int col = jrow + r16;
                float dv[4] = {d0, d1, d2, d3};
                #pragma unroll
                for (int r = 0; r < 4; ++r) {
                    int rowg = irow + g * 4 + r;
                    if (dv[r] < 88.0f && rowg != col)
                        osum[r] += __expf(-fmaxf(dv[r], 0.0f));
                }
            }
        }
        #pragma unroll
        for (int off = 1; off < 16; off <<= 1)
            #pragma unroll
            for (int r = 0; r < 4; ++r)
                osum[r] += __shfl_xor(osum[r], off, 16);
        if (r16 == 0) {
            #pragma unroll
            for (int r = 0; r < 4; ++r) {
                int rowg = irow + g * 4 + r;
                out[(size_t)rowg * OUT_STRIDE + IN_F + b] = osum[r];
            }
        }
    }
}

// ---------------------------------------------------------------------------
extern "C" void kernel_launch(void* const* d_in, const int* in_sizes, int n_in,
                              void* d_out, int out_size, void* d_ws, size_t ws_size,
                              hipStream_t stream) {
    const float* x = (const float*)d_in[0];   // [1024,1024] fp32
    const float* T = (const float*)d_in[1];   // [1024,2048] fp32
    float* out = (float*)d_out;               // [1024,1152] fp32

    // workspace layout (needs 10 MiB):
    //   xb  : 1024*1024 bf16 = 2 MiB
    //   Tt  : 2048*1024 bf16 = 4 MiB  (transposed: [col][k])
    //   Mws : 128*1024*16 bf16 = 4 MiB ([b][row][k])
    char* ws = (char*)d_ws;
    short* xb  = (short*)(ws);
    short* Tt  = (short*)(ws + (2u << 20));
    short* Mws = (short*)(ws + (6u << 20));

    kx_cast_copy<<<dim3(1024), dim3(256), 0, stream>>>(x, out, xb);
    k0_transpose<<<dim3(NCOL / TC, IN_F / TK), dim3(256), 0, stream>>>(T, Tt);
    k1_gemm<<<dim3(NCOL / BN, N_ROWS / BM), dim3(256), 0, stream>>>(xb, Tt, Mws);
    k2_kernelsum<<<dim3(8, OUT_F), dim3(256), 0, stream>>>(Mws, out);
}

// Round 2
// 71.386 us; speedup vs baseline: 1.1178x; 1.1178x over previous
//
#include <hip/hip_runtime.h>
#include <hip/hip_bf16.h>
#include <stdint.h>

#define N_ROWS 1024
#define IN_F   1024
#define OUT_F  128
#define KDIM   16
#define NCOL   2048
#define OUT_STRIDE 1152

typedef __attribute__((ext_vector_type(8)))  short bf16x8;
typedef __attribute__((ext_vector_type(4)))  short s16x4;
typedef __attribute__((ext_vector_type(4)))  float f32x4;
typedef __attribute__((ext_vector_type(16))) float f32x16;

__device__ __forceinline__ short f2b(float f) {
    uint32_t u = __float_as_uint(f);
    uint32_t r = u + 0x7fffu + ((u >> 16) & 1u);
    return (short)(r >> 16);
}
__device__ __forceinline__ float b2f(short s) {
    return __uint_as_float(((uint32_t)(uint16_t)s) << 16);
}
__device__ __forceinline__ void gload16(const void* g, void* l) {
    __builtin_amdgcn_global_load_lds((const __attribute__((address_space(1))) void*)g,
                                     (__attribute__((address_space(3))) void*)l, 16, 0, 0);
}

// ---------------------------------------------------------------------------
// kprep: blocks 0..1023  : out[:, :1024] = x (exact) and xb = bf16(x)
//        blocks 1024..1535: Tt[col][k] = bf16(T[k][col])  (64x64 LDS transpose)
__global__ __launch_bounds__(256) void kprep(const float* __restrict__ x,
                                             const float* __restrict__ T,
                                             float* __restrict__ out,
                                             short* __restrict__ xb,
                                             short* __restrict__ Tt) {
    __shared__ short lds[64 * 72];
    int bid = blockIdx.x;
    int t   = threadIdx.x;
    if (bid < 1024) {
        int row = bid, c4 = t;
        float4 v = *reinterpret_cast<const float4*>(x + row * IN_F + c4 * 4);
        *reinterpret_cast<float4*>(out + row * OUT_STRIDE + c4 * 4) = v;
        s16x4 h;
        h[0] = f2b(v.x); h[1] = f2b(v.y); h[2] = f2b(v.z); h[3] = f2b(v.w);
        *reinterpret_cast<s16x4*>(xb + row * IN_F + c4 * 4) = h;
    } else {
        int b2 = bid - 1024;             // 0..511
        int cbase = (b2 & 31) * 64;      // 32 col-blocks
        int kbase = (b2 >> 5) * 64;      // 16 k-blocks
        #pragma unroll
        for (int it = 0; it < 4; ++it) {
            int id = t + it * 256;
            int k = id >> 4, c4 = id & 15;
            float4 v = *reinterpret_cast<const float4*>(T + (size_t)(kbase + k) * NCOL + cbase + c4 * 4);
            int c0 = c4 * 4;
            lds[(c0 + 0) * 72 + k] = f2b(v.x);
            lds[(c0 + 1) * 72 + k] = f2b(v.y);
            lds[(c0 + 2) * 72 + k] = f2b(v.z);
            lds[(c0 + 3) * 72 + k] = f2b(v.w);
        }
        __syncthreads();
        #pragma unroll
        for (int it = 0; it < 2; ++it) {
            int id = t + it * 256;
            int col = id >> 3, part = id & 7;
            bf16x8 w2 = *reinterpret_cast<const bf16x8*>(&lds[col * 72 + part * 8]);
            *reinterpret_cast<bf16x8*>(Tt + (size_t)(cbase + col) * IN_F + kbase + part * 8) = w2;
        }
    }
}

// ---------------------------------------------------------------------------
// k1: M = xb @ T via 16x16x32 bf16 MFMA.  BM=64, BN=128, BK=64, 4 waves (2x2),
// wave tile 32x64.  global_load_lds (16B) staging, linear LDS dest,
// pre-swizzled source + XOR-swizzled ds_read; 2-phase prefetch pipeline.
__global__ __launch_bounds__(256) void k1_gemm(const short* __restrict__ xb,
                                               const short* __restrict__ Tt,
                                               short* __restrict__ Mws) {
    __shared__ short Al[2][64][64];    // 16 KB
    __shared__ short Bl[2][128][64];   // 32 KB
    int t = threadIdx.x;
    int l = t & 63, w = t >> 6;
    int wr = w >> 1, wc = w & 1;
    int g = l >> 4, r16 = l & 15;
    int rowbase = blockIdx.y * 64;
    int colbase = blockIdx.x * 128;
    f32x4 acc[2][4] = {};

    auto STAGE = [&](int kt, int bsel) {
        #pragma unroll
        for (int rnd = 0; rnd < 2; ++rnd) {        // A: 512 x 16B chunks
            int c = t + rnd * 256;
            int row = c >> 3, slot = c & 7;
            int sp = slot ^ (row & 7);
            gload16(xb + (size_t)(rowbase + row) * IN_F + kt + sp * 8,
                    &Al[bsel][0][0] + c * 8);
        }
        #pragma unroll
        for (int rnd = 0; rnd < 4; ++rnd) {        // B: 1024 x 16B chunks
            int c = t + rnd * 256;
            int col = c >> 3, slot = c & 7;
            int sp = slot ^ (col & 7);
            gload16(Tt + (size_t)(colbase + col) * IN_F + kt + sp * 8,
                    &Bl[bsel][0][0] + c * 8);
        }
    };

    STAGE(0, 0);
    __syncthreads();                    // compiler drains vmcnt(0) before barrier
    int buf = 0;
    for (int step = 0; step < 16; ++step) {
        if (step < 15) STAGE((step + 1) * 64, buf ^ 1);   // prefetch next tile
        const short* Ab = &Al[buf][0][0];
        const short* Bb = &Bl[buf][0][0];
        #pragma unroll
        for (int h = 0; h < 2; ++h) {
            int sl = ((h * 4 + g) ^ (r16 & 7)) * 8;
            bf16x8 a2[2], b4[4];
            #pragma unroll
            for (int m = 0; m < 2; ++m)
                a2[m] = *reinterpret_cast<const bf16x8*>(Ab + (wr * 32 + m * 16 + r16) * 64 + sl);
            #pragma unroll
            for (int n = 0; n < 4; ++n)
                b4[n] = *reinterpret_cast<const bf16x8*>(Bb + (wc * 64 + n * 16 + r16) * 64 + sl);
            #pragma unroll
            for (int m = 0; m < 2; ++m)
                #pragma unroll
                for (int n = 0; n < 4; ++n)
                    acc[m][n] = __builtin_amdgcn_mfma_f32_16x16x32_bf16(a2[m], b4[n], acc[m][n], 0, 0, 0);
        }
        __syncthreads();               // drains prefetch vmcnt + protects buf reuse
        buf ^= 1;
    }

    // epilogue: C[row][col] -> Mws[(col>>4)][row][col&15] bf16 (v1-verified)
    #pragma unroll
    for (int m = 0; m < 2; ++m)
        #pragma unroll
        for (int n = 0; n < 4; ++n) {
            int col = colbase + wc * 64 + n * 16 + r16;
            int bb = col >> 4, kk = col & 15;
            #pragma unroll
            for (int r = 0; r < 4; ++r) {
                int row = rowbase + wr * 32 + m * 16 + g * 4 + r;
                Mws[(size_t)((bb << 10) + row) * KDIM + kk] = f2b(acc[m][n][r]);
            }
        }
}

// ---------------------------------------------------------------------------
// k2: o[i,b] = sum_{j != i} exp(-max(sq_i+sq_j-2*M_i.M_j,0)) via 32x32x16 MFMA
// (K=16 exact).  LDS: Mt[khalf][row][8] (16B rows, conflict-free b128), sq[1024].
// Fast path per 32x32 tile: conservative trigger 2*cmax - sqj > min(sqi)-88.
__global__ __launch_bounds__(256) void k2_kernelsum(const short* __restrict__ Mws,
                                                    float* __restrict__ out) {
    __shared__ short Mt[2][N_ROWS][8];   // 32 KB
    __shared__ float sq[N_ROWS];         //  4 KB
    int b = blockIdx.y;
    int t = threadIdx.x;
    const short* Mb = Mws + ((size_t)b << 14);   // b*1024*16

    #pragma unroll
    for (int rnd = 0; rnd < 4; ++rnd) {          // stage + sq in one pass
        int row = t + rnd * 256;
        bf16x8 lo = *reinterpret_cast<const bf16x8*>(Mb + row * KDIM);
        bf16x8 hi = *reinterpret_cast<const bf16x8*>(Mb + row * KDIM + 8);
        *reinterpret_cast<bf16x8*>(&Mt[0][row][0]) = lo;
        *reinterpret_cast<bf16x8*>(&Mt[1][row][0]) = hi;
        float s = 0.f;
        #pragma unroll
        for (int k = 0; k < 8; ++k) {
            float f0 = b2f(lo[k]), f1 = b2f(hi[k]);
            s += f0 * f0 + f1 * f1;
        }
        sq[row] = s;
    }
    __syncthreads();

    int l = t & 63, w = t >> 6;
    int hi5 = l >> 5, c31 = l & 31;
    int irow = (blockIdx.x * 4 + w) * 32;

    bf16x8 a = *reinterpret_cast<const bf16x8*>(&Mt[hi5][irow + c31][0]);
    float sqi[16];
    #pragma unroll
    for (int r = 0; r < 16; ++r) sqi[r] = sq[irow + (r & 3) + 8 * (r >> 2) + 4 * hi5];
    float smin = sqi[0];
    #pragma unroll
    for (int r = 1; r < 16; ++r) smin = fminf(smin, sqi[r]);
    smin = fminf(smin, __shfl_xor(smin, 32));
    float Cs = smin - 88.0f;

    float osum[16] = {};
    const short* mtb = &Mt[hi5][c31][0];
    const float* sqb = &sq[c31];
    f32x16 zro = {};

    #pragma unroll 8
    for (int jt = 0; jt < 32; ++jt) {
        bf16x8 bf = *reinterpret_cast<const bf16x8*>(mtb + jt * 256);
        float sqj = sqb[jt * 32];
        f32x16 c = __builtin_amdgcn_mfma_f32_32x32x16_bf16(a, bf, zro, 0, 0, 0);
        float m0 = fmaxf(fmaxf(c[0], c[1]), fmaxf(c[2], c[3]));
        float m1 = fmaxf(fmaxf(c[4], c[5]), fmaxf(c[6], c[7]));
        float m2 = fmaxf(fmaxf(c[8], c[9]), fmaxf(c[10], c[11]));
        float m3 = fmaxf(fmaxf(c[12], c[13]), fmaxf(c[14], c[15]));
        float cm = fmaxf(fmaxf(m0, m1), fmaxf(m2, m3));
        if (__ballot(fmaf(2.f, cm, -sqj) > Cs)) {    // diagonal tiles + rare near-pairs
            int jcol = jt * 32 + c31;
            #pragma unroll
            for (int r = 0; r < 16; ++r) {
                float d = fmaf(-2.f, c[r], sqi[r] + sqj);
                int rowr = irow + (r & 3) + 8 * (r >> 2) + 4 * hi5;
                if (d < 88.f && rowr != jcol)
                    osum[r] += __expf(-fmaxf(d, 0.f));
            }
        }
    }
    #pragma unroll
    for (int off = 1; off < 32; off <<= 1)
        #pragma unroll
        for (int r = 0; r < 16; ++r)
            osum[r] += __shfl_xor(osum[r], off);
    if (c31 == 0) {
        #pragma unroll
        for (int r = 0; r < 16; ++r) {
            int rowr = irow + (r & 3) + 8 * (r >> 2) + 4 * hi5;
            out[(size_t)rowr * OUT_STRIDE + IN_F + b] = osum[r];
        }
    }
}

// ---------------------------------------------------------------------------
extern "C" void kernel_launch(void* const* d_in, const int* in_sizes, int n_in,
                              void* d_out, int out_size, void* d_ws, size_t ws_size,
                              hipStream_t stream) {
    const float* x = (const float*)d_in[0];   // [1024,1024] fp32
    const float* T = (const float*)d_in[1];   // [1024,2048] fp32
    float* out = (float*)d_out;               // [1024,1152] fp32

    char* ws = (char*)d_ws;
    short* xb  = (short*)(ws);                // 2 MiB
    short* Tt  = (short*)(ws + (2u << 20));   // 4 MiB  [col][k]
    short* Mws = (short*)(ws + (6u << 20));   // 4 MiB  [b][row][k]

    kprep<<<dim3(1536), dim3(256), 0, stream>>>(x, T, out, xb, Tt);
    k1_gemm<<<dim3(16, 16), dim3(256), 0, stream>>>(xb, Tt, Mws);
    k2_kernelsum<<<dim3(8, OUT_F), dim3(256), 0, stream>>>(Mws, out);
}

// Round 3
// 43.191 us; speedup vs baseline: 1.8475x; 1.6528x over previous
//
#include <hip/hip_runtime.h>
#include <hip/hip_bf16.h>
#include <stdint.h>

#define N_ROWS 1024
#define IN_F   1024
#define OUT_F  128
#define KDIM   16
#define NCOL   2048
#define OUT_STRIDE 1152

typedef __attribute__((ext_vector_type(8)))  short bf16x8;
typedef __attribute__((ext_vector_type(4)))  short s16x4;
typedef __attribute__((ext_vector_type(4)))  float f32x4;
typedef __attribute__((ext_vector_type(16))) float f32x16;

__device__ __forceinline__ short f2b(float f) {
    uint32_t u = __float_as_uint(f);
    uint32_t r = u + 0x7fffu + ((u >> 16) & 1u);
    return (short)(r >> 16);
}
__device__ __forceinline__ float b2f(short s) {
    return __uint_as_float(((uint32_t)(uint16_t)s) << 16);
}
__device__ __forceinline__ void gload16(const void* g, void* l) {
    __builtin_amdgcn_global_load_lds((const __attribute__((address_space(1))) void*)g,
                                     (__attribute__((address_space(3))) void*)l, 16, 0, 0);
}

// ---------------------------------------------------------------------------
// kprep: blocks 0..1023  : out[:, :1024] = x (exact) and xb = bf16(x)
//        blocks 1024..1535: Tt[col][k] = bf16(T[k][col])  (64x64 LDS transpose)
__global__ __launch_bounds__(256) void kprep(const float* __restrict__ x,
                                             const float* __restrict__ T,
                                             float* __restrict__ out,
                                             short* __restrict__ xb,
                                             short* __restrict__ Tt) {
    __shared__ short lds[64 * 72];
    int bid = blockIdx.x;
    int t   = threadIdx.x;
    if (bid < 1024) {
        int row = bid, c4 = t;
        float4 v = *reinterpret_cast<const float4*>(x + row * IN_F + c4 * 4);
        *reinterpret_cast<float4*>(out + row * OUT_STRIDE + c4 * 4) = v;
        s16x4 h;
        h[0] = f2b(v.x); h[1] = f2b(v.y); h[2] = f2b(v.z); h[3] = f2b(v.w);
        *reinterpret_cast<s16x4*>(xb + row * IN_F + c4 * 4) = h;
    } else {
        int b2 = bid - 1024;             // 0..511
        int cbase = (b2 & 31) * 64;      // 32 col-blocks
        int kbase = (b2 >> 5) * 64;      // 16 k-blocks
        #pragma unroll
        for (int it = 0; it < 4; ++it) {
            int id = t + it * 256;
            int k = id >> 4, c4 = id & 15;
            float4 v = *reinterpret_cast<const float4*>(T + (size_t)(kbase + k) * NCOL + cbase + c4 * 4);
            int c0 = c4 * 4;
            lds[(c0 + 0) * 72 + k] = f2b(v.x);
            lds[(c0 + 1) * 72 + k] = f2b(v.y);
            lds[(c0 + 2) * 72 + k] = f2b(v.z);
            lds[(c0 + 3) * 72 + k] = f2b(v.w);
        }
        __syncthreads();
        #pragma unroll
        for (int it = 0; it < 2; ++it) {
            int id = t + it * 256;
            int col = id >> 3, part = id & 7;
            bf16x8 w2 = *reinterpret_cast<const bf16x8*>(&lds[col * 72 + part * 8]);
            *reinterpret_cast<bf16x8*>(Tt + (size_t)(cbase + col) * IN_F + kbase + part * 8) = w2;
        }
    }
}

// ---------------------------------------------------------------------------
// k1: M = xb @ T via 16x16x32 bf16 MFMA.  BM=64, BN=128, BK=64, 4 waves (2x2),
// wave tile 32x64.  global_load_lds (16B) staging, linear LDS dest,
// pre-swizzled source + XOR-swizzled ds_read; 2-phase prefetch pipeline.
__global__ __launch_bounds__(256) void k1_gemm(const short* __restrict__ xb,
                                               const short* __restrict__ Tt,
                                               short* __restrict__ Mws) {
    __shared__ short Al[2][64][64];    // 16 KB
    __shared__ short Bl[2][128][64];   // 32 KB
    int t = threadIdx.x;
    int l = t & 63, w = t >> 6;
    int wr = w >> 1, wc = w & 1;
    int g = l >> 4, r16 = l & 15;
    int rowbase = blockIdx.y * 64;
    int colbase = blockIdx.x * 128;
    f32x4 acc[2][4] = {};

    auto STAGE = [&](int kt, int bsel) {
        #pragma unroll
        for (int rnd = 0; rnd < 2; ++rnd) {        // A: 512 x 16B chunks
            int c = t + rnd * 256;
            int row = c >> 3, slot = c & 7;
            int sp = slot ^ (row & 7);
            gload16(xb + (size_t)(rowbase + row) * IN_F + kt + sp * 8,
                    &Al[bsel][0][0] + c * 8);
        }
        #pragma unroll
        for (int rnd = 0; rnd < 4; ++rnd) {        // B: 1024 x 16B chunks
            int c = t + rnd * 256;
            int col = c >> 3, slot = c & 7;
            int sp = slot ^ (col & 7);
            gload16(Tt + (size_t)(colbase + col) * IN_F + kt + sp * 8,
                    &Bl[bsel][0][0] + c * 8);
        }
    };

    STAGE(0, 0);
    __syncthreads();
    int buf = 0;
    for (int step = 0; step < 16; ++step) {
        if (step < 15) STAGE((step + 1) * 64, buf ^ 1);   // prefetch next tile
        const short* Ab = &Al[buf][0][0];
        const short* Bb = &Bl[buf][0][0];
        #pragma unroll
        for (int h = 0; h < 2; ++h) {
            int sl = ((h * 4 + g) ^ (r16 & 7)) * 8;
            bf16x8 a2[2], b4[4];
            #pragma unroll
            for (int m = 0; m < 2; ++m)
                a2[m] = *reinterpret_cast<const bf16x8*>(Ab + (wr * 32 + m * 16 + r16) * 64 + sl);
            #pragma unroll
            for (int n = 0; n < 4; ++n)
                b4[n] = *reinterpret_cast<const bf16x8*>(Bb + (wc * 64 + n * 16 + r16) * 64 + sl);
            #pragma unroll
            for (int m = 0; m < 2; ++m)
                #pragma unroll
                for (int n = 0; n < 4; ++n)
                    acc[m][n] = __builtin_amdgcn_mfma_f32_16x16x32_bf16(a2[m], b4[n], acc[m][n], 0, 0, 0);
        }
        __syncthreads();
        buf ^= 1;
    }

    // epilogue: C[row][col] -> Mws[(col>>4)][row][col&15] bf16 (v1-verified)
    #pragma unroll
    for (int m = 0; m < 2; ++m)
        #pragma unroll
        for (int n = 0; n < 4; ++n) {
            int col = colbase + wc * 64 + n * 16 + r16;
            int bb = col >> 4, kk = col & 15;
            #pragma unroll
            for (int r = 0; r < 4; ++r) {
                int row = rowbase + wr * 32 + m * 16 + g * 4 + r;
                Mws[(size_t)((bb << 10) + row) * KDIM + kk] = f2b(acc[m][n][r]);
            }
        }
}

// ---------------------------------------------------------------------------
// k2: o[i,b] = sum_{j != i} exp(-max(sq_i+sq_j-2*M_i.M_j,0)) via 32x32x16 MFMA
// (K=16 exact).  2 i-tiles per wave, grid (4,128).
// EXACT per-lane trigger: dmin = min_r(sqi[r]-2c[r]) + sqj < 88 -> slow path
// fires only on diagonal tiles (1/32) + genuine near-pairs.
__global__ __launch_bounds__(256) void k2_kernelsum(const short* __restrict__ Mws,
                                                    float* __restrict__ out) {
    __shared__ short Mt[2][N_ROWS][8];   // 32 KB
    __shared__ float sq[N_ROWS];         //  4 KB
    int b = blockIdx.y;
    int t = threadIdx.x;
    const short* Mb = Mws + ((size_t)b << 14);   // b*1024*16

    #pragma unroll
    for (int rnd = 0; rnd < 4; ++rnd) {          // stage + sq in one pass
        int row = t + rnd * 256;
        bf16x8 lo = *reinterpret_cast<const bf16x8*>(Mb + row * KDIM);
        bf16x8 hi = *reinterpret_cast<const bf16x8*>(Mb + row * KDIM + 8);
        *reinterpret_cast<bf16x8*>(&Mt[0][row][0]) = lo;
        *reinterpret_cast<bf16x8*>(&Mt[1][row][0]) = hi;
        float s = 0.f;
        #pragma unroll
        for (int k = 0; k < 8; ++k) {
            float f0 = b2f(lo[k]), f1 = b2f(hi[k]);
            s += f0 * f0 + f1 * f1;
        }
        sq[row] = s;
    }
    __syncthreads();

    int l = t & 63, w = t >> 6;
    int hi5 = l >> 5, c31 = l & 31;

    int irowA[2];
    bf16x8 a[2];
    float sqi[2][16];
    #pragma unroll
    for (int it = 0; it < 2; ++it) {
        irowA[it] = (blockIdx.x * 8 + w * 2 + it) * 32;
        a[it] = *reinterpret_cast<const bf16x8*>(&Mt[hi5][irowA[it] + c31][0]);
        #pragma unroll
        for (int r = 0; r < 16; ++r)
            sqi[it][r] = sq[irowA[it] + (r & 3) + 8 * (r >> 2) + 4 * hi5];
    }

    float osum[2][16] = {};
    const short* mtb = &Mt[hi5][c31][0];
    const float* sqb = &sq[c31];
    f32x16 zro = {};

    for (int jt = 0; jt < 32; ++jt) {
        bf16x8 bf = *reinterpret_cast<const bf16x8*>(mtb + jt * 256);
        float sqj = sqb[jt * 32];
        #pragma unroll
        for (int it = 0; it < 2; ++it) {
            f32x16 c = __builtin_amdgcn_mfma_f32_32x32x16_bf16(a[it], bf, zro, 0, 0, 0);
            float dr[16];
            #pragma unroll
            for (int r = 0; r < 16; ++r)
                dr[r] = fmaf(-2.f, c[r], sqi[it][r]);
            // min tree (folds to v_min3)
            float m0 = fminf(fminf(dr[0],  dr[1]),  fminf(dr[2],  dr[3]));
            float m1 = fminf(fminf(dr[4],  dr[5]),  fminf(dr[6],  dr[7]));
            float m2 = fminf(fminf(dr[8],  dr[9]),  fminf(dr[10], dr[11]));
            float m3 = fminf(fminf(dr[12], dr[13]), fminf(dr[14], dr[15]));
            float dmin = fminf(fminf(m0, m1), fminf(m2, m3));
            if (__ballot(dmin + sqj < 88.0f)) {      // exact: diag tiles + near-pairs
                int jcol = jt * 32 + c31;
                #pragma unroll
                for (int r = 0; r < 16; ++r) {
                    float d = dr[r] + sqj;
                    int rowr = irowA[it] + (r & 3) + 8 * (r >> 2) + 4 * hi5;
                    if (d < 88.f && rowr != jcol)
                        osum[it][r] += __expf(-fmaxf(d, 0.f));
                }
            }
        }
    }

    #pragma unroll
    for (int it = 0; it < 2; ++it) {
        float tot = 0.f;
        #pragma unroll
        for (int r = 0; r < 16; ++r) tot += osum[it][r];
        if (__ballot(tot != 0.f)) {                  // skip reduce when all-zero
            #pragma unroll
            for (int off = 1; off < 32; off <<= 1)
                #pragma unroll
                for (int r = 0; r < 16; ++r)
                    osum[it][r] += __shfl_xor(osum[it][r], off);
        }
        if (c31 == 0) {
            #pragma unroll
            for (int r = 0; r < 16; ++r) {
                int rowr = irowA[it] + (r & 3) + 8 * (r >> 2) + 4 * hi5;
                out[(size_t)rowr * OUT_STRIDE + IN_F + b] = osum[it][r];
            }
        }
    }
}

// ---------------------------------------------------------------------------
extern "C" void kernel_launch(void* const* d_in, const int* in_sizes, int n_in,
                              void* d_out, int out_size, void* d_ws, size_t ws_size,
                              hipStream_t stream) {
    const float* x = (const float*)d_in[0];   // [1024,1024] fp32
    const float* T = (const float*)d_in[1];   // [1024,2048] fp32
    float* out = (float*)d_out;               // [1024,1152] fp32

    char* ws = (char*)d_ws;
    short* xb  = (short*)(ws);                // 2 MiB
    short* Tt  = (short*)(ws + (2u << 20));   // 4 MiB  [col][k]
    short* Mws = (short*)(ws + (6u << 20));   // 4 MiB  [b][row][k]

    kprep<<<dim3(1536), dim3(256), 0, stream>>>(x, T, out, xb, Tt);
    k1_gemm<<<dim3(16, 16), dim3(256), 0, stream>>>(xb, Tt, Mws);
    k2_kernelsum<<<dim3(4, OUT_F), dim3(256), 0, stream>>>(Mws, out);
}